// Round 5
// baseline (336.421 us; speedup 1.0000x reference)
//
#include <hip/hip_runtime.h>
#include <math.h>

#define B_ 256
#define L_ 100
#define H_ 8

// Output offsets (floats): V[B,L,H,64], series[B,H,L,L], prior, sig, M[B,H,L]
#define OFF_SERIES ((size_t)B_ * L_ * H_ * 64)
#define OFF_PRIOR  (OFF_SERIES + (size_t)B_ * H_ * L_ * L_)
#define OFF_SIG    (OFF_PRIOR  + (size_t)B_ * H_ * L_ * L_)
#define OFF_M      (OFF_SIG    + (size_t)B_ * H_ * L_ * L_)

#define LOG2E 1.4426950408889634f
#define LN3   1.0986122886681098f
#define INV_SQRT_2PI 0.3989422804014327f

typedef __attribute__((ext_vector_type(8))) short short8b;  // 8 bf16
typedef __attribute__((ext_vector_type(4))) float f32x4;

// LDS layout (bytes)
#define KHI 0          // K hi bf16, [100][64], row-swizzled, 12800
#define KLO 12800      // K lo
#define QP  25600      // Q hi (12800); after B-frag load: P region 4x6400
#define QLO 38400      // Q lo
#define VLT 51200      // V^T f32 [64][104] swizzled (26624) + 256 slack
#define DEN 78080      // 64 f32
#define SMEM_BYTES 78336

__device__ __forceinline__ void cvt_split8(const float* f, short8b& hi, short8b& lo) {
#pragma unroll
    for (int i = 0; i < 8; ++i) {
        unsigned u = __float_as_uint(f[i]);
        hi[i] = (short)(u >> 16);
        float r = f[i] - __uint_as_float(u & 0xFFFF0000u);
        lo[i] = (short)(__float_as_uint(r) >> 16);
    }
}

__global__ __launch_bounds__(256) void fused_kernel(
    const float* __restrict__ Q, const float* __restrict__ K,
    const float* __restrict__ Vin, const float* __restrict__ sigma,
    const float* __restrict__ dist, float* __restrict__ Vout,
    float* __restrict__ series, float* __restrict__ prior,
    float* __restrict__ sigout, float* __restrict__ Mout) {
    const int bid = blockIdx.x;
    const int b = bid >> 3, h = bid & 7;
    __shared__ __align__(16) char smem[SMEM_BYTES];
    float* den_s = (float*)(smem + DEN);
    const int t = threadIdx.x;

    // ---- Phase B: stage Q,K as split-bf16 hi/lo (row XOR-swizzle) ----
    for (int pass = 0; pass < 2; ++pass) {
        const float* Mt = pass ? K : Q;
        const int hioff = pass ? KHI : QP;
        const int looff = pass ? KLO : QLO;
        for (int ci = t; ci < 800; ci += 256) {
            int row = ci >> 3, c8 = ci & 7;
            const float* src = Mt + ((size_t)(b * L_ + row) * H_ + h) * 64 + c8 * 8;
            float4 f0 = *(const float4*)src;
            float4 f1 = *(const float4*)(src + 4);
            float f[8] = {f0.x, f0.y, f0.z, f0.w, f1.x, f1.y, f1.z, f1.w};
            short8b hi8, lo8;
            cvt_split8(f, hi8, lo8);
            int byte = (row * 128 + c8 * 16) ^ ((row & 7) << 4);
            *(short8b*)(smem + hioff + byte) = hi8;
            *(short8b*)(smem + looff + byte) = lo8;
        }
    }
    // ---- stage V^T f32 [64][104] with bijective byte-XOR swizzle ----
    for (int f = t; f < 1600; f += 256) {
        int j = f >> 4, c = f & 15;
        float4 v = *(const float4*)(Vin + ((size_t)(b * L_ + j) * H_ + h) * 64 + c * 4);
        float vv[4] = {v.x, v.y, v.z, v.w};
#pragma unroll
        for (int i = 0; i < 4; ++i) {
            int d = c * 4 + i;
            int ab = (d * 416 + j * 4) ^ (((d >> 2) & 7) << 5);
            *(float*)(smem + VLT + ab) = vv[i];
        }
    }
    if (t < 64) {   // zero V^T cols 100..103 (k-tail safety)
#pragma unroll
        for (int j = 100; j < 104; ++j) {
            int ab = (t * 416 + j * 4) ^ (((t >> 2) & 7) << 5);
            *(float*)(smem + VLT + ab) = 0.f;
        }
    }
    __syncthreads();

    const int wave = t >> 6;
    const int lane = t & 63;
    const int lr = lane & 15;   // P-tile row / output col l-offset
    const int g  = lane >> 4;   // k-group

    // ---- B-frags (Q^T) for this wave's l-tiles; then Q region is dead ----
    const int nt = (wave < 3) ? 2 : 1;
    short8b qh[2][2], ql[2][2];
    for (int ti = 0; ti < nt; ++ti) {
        int lt = wave * 2 + ti;
        int lrow = lt * 16 + lr; if (lrow > 99) lrow = 99;
        int rb = lrow * 128, sw = (lrow & 7) << 4;
#pragma unroll
        for (int es = 0; es < 2; ++es) {
            int byte = (rb + g * 16 + es * 64) ^ sw;
            qh[ti][es] = *(const short8b*)(smem + QP + byte);
            ql[ti][es] = *(const short8b*)(smem + QLO + byte);
        }
    }
    __syncthreads();   // B-frags loaded -> P staging may reuse Q region

    const float cs = 0.125f * LOG2E;
    const size_t bh = (size_t)(b * H_ + h);
    char* pbase = smem + QP + wave * 6400;   // [16][100] f32 per wave

    for (int ti = 0; ti < nt; ++ti) {
        const int lt = wave * 2 + ti;
        const int l = lt * 16 + lr;     // this lane's column (may be >=100)

        // ======== Phase C: scores, stats, series, M (R4-proven) ========
        float m1 = -INFINITY, m2 = -INFINITY, sum1 = 0.f, sum2 = 0.f, den = 0.f;
        for (int jt = 0; jt < 7; ++jt) {
            int jrow = jt * 16 + lr; if (jrow > 99) jrow = 99;
            int rb = jrow * 128, sw = (jrow & 7) << 4;
            f32x4 C = {0.f, 0.f, 0.f, 0.f};
#pragma unroll
            for (int es = 0; es < 2; ++es) {
                int byte = (rb + g * 16 + es * 64) ^ sw;
                short8b kh = *(const short8b*)(smem + KHI + byte);
                short8b kl = *(const short8b*)(smem + KLO + byte);
                C = __builtin_amdgcn_mfma_f32_16x16x32_bf16(kh, qh[ti][es], C, 0, 0, 0);
                C = __builtin_amdgcn_mfma_f32_16x16x32_bf16(kh, ql[ti][es], C, 0, 0, 0);
                C = __builtin_amdgcn_mfma_f32_16x16x32_bf16(kl, qh[ti][es], C, 0, 0, 0);
            }
            f32x4 pw = {0.f, 0.f, 0.f, 0.f};
#pragma unroll
            for (int r = 0; r < 4; ++r) {
                int j = jt * 16 + g * 4 + r;
                float s = C[r];
                if (j < 100) {
                    m1 = fmaxf(m1, s);
                    sum1 += s;
                    bool band = (j - l < 3) && (l - j < 3);
                    float sp = band ? 0.f : s;
                    m2 = fmaxf(m2, sp);
                    sum2 += sp;
                    float p = exp2f(s * cs);
                    den += p;                       // diag included in den
                    pw[r] = (j == l) ? 0.f : p;     // diag zeroed in output
                }
            }
            if (!(jt == 6 && g > 0))
                *(f32x4*)(pbase + lr * 400 + jt * 64 + g * 16) = pw;
        }
        m1   = fmaxf(m1, __shfl_xor(m1, 16, 64));
        m1   = fmaxf(m1, __shfl_xor(m1, 32, 64));
        m2   = fmaxf(m2, __shfl_xor(m2, 16, 64));
        m2   = fmaxf(m2, __shfl_xor(m2, 32, 64));
        sum1 += __shfl_xor(sum1, 16, 64);
        sum1 += __shfl_xor(sum1, 32, 64);
        sum2 += __shfl_xor(sum2, 16, 64);
        sum2 += __shfl_xor(sum2, 32, 64);
        den  += __shfl_xor(den, 16, 64);
        den  += __shfl_xor(den, 32, 64);
        if (lane < 16 && l < 100) {
            den_s[wave * 16 + lr] = den;
            float M1 = m1 - sum1 * (1.0f / 100.0f);
            float M2 = m2 - sum2 * (1.0f / 94.0f);
            Mout[bh * L_ + l] = M1 - M2;
        }
        // normalize + coalesced series copy-out
        for (int f = lane; f < 400; f += 64) {
            int row = f / 25, c = f - row * 25;
            int lg = lt * 16 + row;
            if (lg < 100) {
                f32x4 p = *(const f32x4*)(pbase + row * 400 + c * 16);
                float invd = 1.0f / den_s[wave * 16 + row];
                p.x *= invd; p.y *= invd; p.z *= invd; p.w *= invd;
                *(f32x4*)(series + (bh * L_ + lg) * L_ + c * 4) = p;
            }
        }

        // ======== Phase D: (PV)^T = V^T . P^T via split-bf16 MFMA ========
        {
            const float invd = 1.0f / den_s[wave * 16 + lr];  // lane-local l
            f32x4 acc[4] = {{0.f,0.f,0.f,0.f},{0.f,0.f,0.f,0.f},
                            {0.f,0.f,0.f,0.f},{0.f,0.f,0.f,0.f}};
            for (int jt32 = 0; jt32 < 4; ++jt32) {
                float pf[8];
                if (jt32 < 3) {
                    f32x4 pA = *(const f32x4*)(pbase + lr * 400 + jt32 * 128 + g * 32);
                    f32x4 pB = *(const f32x4*)(pbase + lr * 400 + jt32 * 128 + g * 32 + 16);
                    pf[0]=pA.x; pf[1]=pA.y; pf[2]=pA.z; pf[3]=pA.w;
                    pf[4]=pB.x; pf[5]=pB.y; pf[6]=pB.z; pf[7]=pB.w;
                } else if (g == 0) {   // j 96..99 real, 100..103 -> 0
                    f32x4 pA = *(const f32x4*)(pbase + lr * 400 + 384);
                    pf[0]=pA.x; pf[1]=pA.y; pf[2]=pA.z; pf[3]=pA.w;
                    pf[4]=0.f; pf[5]=0.f; pf[6]=0.f; pf[7]=0.f;
                } else {               // j >= 104: all zero
#pragma unroll
                    for (int i = 0; i < 8; ++i) pf[i] = 0.f;
                }
                short8b Bh, Bl;
                cvt_split8(pf, Bh, Bl);
                // A k-base: clamp tail to j=96 (B=0 kills those k-terms; finite)
                const int j0 = (jt32 == 3) ? 96 : jt32 * 32 + 8 * g;
#pragma unroll
                for (int dt = 0; dt < 4; ++dt) {
                    const int d = dt * 16 + lr;
                    int ab = (d * 416 + j0 * 4) ^ (((d >> 2) & 7) << 5);
                    const char* ap = smem + VLT + ab;
                    f32x4 a0 = *(const f32x4*)ap;
                    f32x4 a1 = *(const f32x4*)(ap + 16);
                    float af[8] = {a0.x, a0.y, a0.z, a0.w, a1.x, a1.y, a1.z, a1.w};
                    short8b Ah, Al;
                    cvt_split8(af, Ah, Al);
                    acc[dt] = __builtin_amdgcn_mfma_f32_16x16x32_bf16(Ah, Bh, acc[dt], 0, 0, 0);
                    acc[dt] = __builtin_amdgcn_mfma_f32_16x16x32_bf16(Ah, Bl, acc[dt], 0, 0, 0);
                    acc[dt] = __builtin_amdgcn_mfma_f32_16x16x32_bf16(Al, Bh, acc[dt], 0, 0, 0);
                }
            }
            if (l < 100) {
#pragma unroll
                for (int dt = 0; dt < 4; ++dt) {
                    f32x4 o = acc[dt];
                    o.x *= invd; o.y *= invd; o.z *= invd; o.w *= invd;
                    // lane holds out[l][dt*16 + g*4 .. +3]
                    *(f32x4*)(Vout + ((size_t)(b * L_ + l) * H_ + h) * 64 + dt * 16 + g * 4) = o;
                }
            }
        }
    }

    // ======== Phase E: prior + sig (independent, write-bound) ========
    {
        const size_t base4 = (size_t)(b * H_ + h) * 2500;
        const float4* d4 = (const float4*)dist;
        float4* p4 = (float4*)prior;
        float4* s4 = (float4*)sigout;
        for (int idx = t; idx < 2500; idx += 256) {
            int l = idx / 25;
            float x = sigma[((size_t)b * L_ + l) * H_ + h];
            float s = 1.0f / (1.0f + exp2f(-5.0f * LOG2E * x)) + 1e-5f;
            float sg = expm1f(s * LN3);   // 3^s - 1, accurate near 0
            float inv = 1.0f / sg;
            float c1 = INV_SQRT_2PI * inv;
            float c2 = 0.5f * LOG2E * inv * inv;
            float4 d = d4[idx];
            float4 pr;
            pr.x = c1 * exp2f(-d.x * d.x * c2);
            pr.y = c1 * exp2f(-d.y * d.y * c2);
            pr.z = c1 * exp2f(-d.z * d.z * c2);
            pr.w = c1 * exp2f(-d.w * d.w * c2);
            p4[base4 + idx] = pr;
            s4[base4 + idx] = make_float4(sg, sg, sg, sg);
        }
    }
}

extern "C" void kernel_launch(void* const* d_in, const int* in_sizes, int n_in,
                              void* d_out, int out_size, void* d_ws, size_t ws_size,
                              hipStream_t stream) {
    const float* Q     = (const float*)d_in[0];
    const float* K     = (const float*)d_in[1];
    const float* V     = (const float*)d_in[2];
    const float* sigma = (const float*)d_in[3];
    const float* dist  = (const float*)d_in[4];

    float* out    = (float*)d_out;
    float* Vout   = out;
    float* series = out + OFF_SERIES;
    float* prior  = out + OFF_PRIOR;
    float* sigout = out + OFF_SIG;
    float* Mout   = out + OFF_M;

    hipLaunchKernelGGL(fused_kernel, dim3(B_ * H_), dim3(256), 0, stream,
                       Q, K, V, sigma, dist, Vout, series, prior, sigout, Mout);
}